// Round 5
// baseline (168.708 us; speedup 1.0000x reference)
//
#include <hip/hip_runtime.h>

// RetrosynthesisAttention, B=16, N=M=D=U=256, fp32.
// logits[b,n,m] = sum_u v[u]*tanh(ep[m,u]+dp[n,u]) (+const); softmax_m; ctx = attn@enc
//
// tanh(x) = 1 - 2/(exp2(Kx)+1), K=2*log2(e); constants cancel in softmax.
// exp2(K(ep+dp)) = E*D precomputed. v folded: z_u = rcpc(v_u)*(2^-16 + E*D)
// = fmaf(E', D*rcpc(v), 2^-16*rcpc(v)) with E' = E*2^-16.
// sum v_u/y_u = 2^16 * sum 1/z_u; EIGHT-way combining -> ONE v_rcp per 8 u's:
//   n4 = (z0+z1)*z2*z3 + (z2+z3)*z0*z1, p4 = z0*z1*z2*z3
//   sum8 = (n4a*p4b + n4b*p4a) / (p4a*p4b)
// rcpc clamp 1e4 keeps |z| >= ~2^-14 -> den8 in [2^-115, 2^80]: safe in fp32.
// Scale folds into LSC = -2^-15 (softmax-invariant).
// encQ layout [b][u/4][m][4]: coalesced float4 per u-quad, reg-double-buffered.

constexpr float KSC   = 2.8853900817779268f;   // 2*log2(e)
constexpr float LOG2E = 1.4426950408889634f;
constexpr float S16   = 1.52587890625e-05f;    // 2^-16
constexpr float LSC   = -3.0517578125e-05f;    // -2^-15

struct F4 { float v[4]; };
__device__ __forceinline__ F4 ld4(const float* p) {
    float4 t = *(const float4*)p;
    F4 r; r.v[0] = t.x; r.v[1] = t.y; r.v[2] = t.z; r.v[3] = t.w; return r;
}
__device__ __forceinline__ float rcp_clamp(float v) {
    float r = __builtin_amdgcn_rcpf(v);
    return fminf(fmaxf(r, -1e4f), 1e4f);   // identical in both kernels
}

// ---------------- Kernel A: projection GEMMs + exp2 epilogue.
// BM=64 rows, BN=64 u, BK=32, 256 thr, 4x4 micro. Only X staged in LDS
// (transposed [k][row], ds_read_b128 coalesced); W read from GLOBAL per k
// (4 distinct 16B/wave, same 64B line, L1-resident, 1-deep prefetch).
// LDS traffic ~0.5 GB total (was ~1.5 GB) -> no longer LDS-bound.
__global__ __launch_bounds__(256) void proj_kernel(
    const float* __restrict__ enc, const float* __restrict__ dec,
    const float* __restrict__ W1,  const float* __restrict__ b1,
    const float* __restrict__ W2,  const float* __restrict__ b2,
    const float* __restrict__ vw,
    float* __restrict__ encQ, float* __restrict__ decE)
{
    __shared__ float Xs[32][65];   // [k][row], stride 65: conflict-benign

    const int tid = threadIdx.x;
    const int tm = tid & 15, tu = tid >> 4;
    const int u0   = blockIdx.x * 64;
    const int row0 = blockIdx.y * 64;          // flat rows 0..8191 (enc|dec)
    const bool is_enc = row0 < 4096;
    const float* X    = is_enc ? enc : dec;
    const float* W    = is_enc ? W1  : W2;
    const float* bias = is_enc ? b1  : b2;
    const int rb   = is_enc ? row0 : row0 - 4096;
    const int ucol = u0 + (tu << 2);
    const float* Wu = W + ucol;

    float acc[4][4] = {};
    for (int kt = 0; kt < 256; kt += 32) {
        __syncthreads();
        #pragma unroll
        for (int i = 0; i < 2; ++i) {          // X[64 rows][32 k] -> Xs[k][row]
            const int f   = tid + (i << 8);
            const int row = f >> 3;            // 0..63
            const int kq  = (f & 7) << 2;      // 0,4,..,28
            F4 x = ld4(&X[(rb + row) * 256 + kt + kq]);
            Xs[kq + 0][row] = x.v[0];
            Xs[kq + 1][row] = x.v[1];
            Xs[kq + 2][row] = x.v[2];
            Xs[kq + 3][row] = x.v[3];
        }
        __syncthreads();
        F4 wv = ld4(&Wu[kt * 256]);            // W row kt (prefetched stream)
        #pragma unroll 8
        for (int k = 0; k < 32; ++k) {
            const int kn = kt + ((k < 31) ? (k + 1) : k);   // uniform select
            const F4 wn = ld4(&Wu[kn * 256]);
            const F4 xa = ld4(&Xs[k][tm << 2]);
            #pragma unroll
            for (int i = 0; i < 4; ++i)
                #pragma unroll
                for (int j = 0; j < 4; ++j)
                    acc[i][j] = fmaf(xa.v[i], wv.v[j], acc[i][j]);
            wv = wn;
        }
    }

    const F4 bb = ld4(&bias[ucol]);
    if (is_enc) {
        const int b  = rb >> 8;
        const int m0 = (rb & 255) + (tm << 2);
        const int q  = ucol >> 2;
        #pragma unroll
        for (int i = 0; i < 4; ++i) {
            float4 o;
            o.x = __builtin_amdgcn_exp2f(fmaf(KSC, acc[i][0] + bb.v[0], -16.f));
            o.y = __builtin_amdgcn_exp2f(fmaf(KSC, acc[i][1] + bb.v[1], -16.f));
            o.z = __builtin_amdgcn_exp2f(fmaf(KSC, acc[i][2] + bb.v[2], -16.f));
            o.w = __builtin_amdgcn_exp2f(fmaf(KSC, acc[i][3] + bb.v[3], -16.f));
            *(float4*)&encQ[b * 65536 + q * 1024 + (m0 + i) * 4] = o;
        }
    } else {
        const F4 vv = ld4(&vw[ucol]);
        float rv[4];
        #pragma unroll
        for (int j = 0; j < 4; ++j) rv[j] = rcp_clamp(vv.v[j]);
        const int r0 = rb + (tm << 2);
        #pragma unroll
        for (int i = 0; i < 4; ++i) {
            float4 o;
            o.x = __builtin_amdgcn_exp2f(KSC * (acc[i][0] + bb.v[0])) * rv[0];
            o.y = __builtin_amdgcn_exp2f(KSC * (acc[i][1] + bb.v[1])) * rv[1];
            o.z = __builtin_amdgcn_exp2f(KSC * (acc[i][2] + bb.v[2])) * rv[2];
            o.w = __builtin_amdgcn_exp2f(KSC * (acc[i][3] + bb.v[3])) * rv[3];
            *(float4*)&decE[(r0 + i) * 256 + ucol] = o;
        }
    }
}

// ---------------- Kernel B: fused logits + softmax + context.
// 256 thr (4 waves), n-tile 4, T=4 chains per thread (E & cq amortized 4x),
// 8-way combining (1 rcp / 8 u's / chain), E reg-double-buffered.
// Grid (64,16)=1024 blocks -> 4 blk/CU, 16 waves/CU.
// dsD/vcs reads are same-address broadcasts (free of conflicts).
__global__ __launch_bounds__(256) void attn_kernel(
    const float* __restrict__ enc,   // [B][M][D]
    const float* __restrict__ encQ,  // [b][u/4][m][4] = exp2(K*ep-16)
    const float* __restrict__ decE,  // [n_flat][u]    = exp2(K*dp)*rcpc(v)
    const float* __restrict__ vw,    // [U]
    float* __restrict__ out_ctx,     // [B][N][D]
    float* __restrict__ out_attn)    // [B][N][M]
{
    __shared__ float dsD[4][256];
    __shared__ float vcs[256];
    __shared__ float attn_s[4][256];
    __shared__ float redm[4][4], reds[4][4];

    const int tid = threadIdx.x;     // 0..255
    const int b   = blockIdx.y;
    const int n0  = blockIdx.x << 2;
    const int m   = tid;

    {   // stage decE rows n0..n0+3 and vcs = 2^-16 * rcpc(v)
        const float* dsrc = decE + (b * 256 + n0) * 256;
        #pragma unroll
        for (int i = 0; i < 4; ++i)
            ((float*)dsD)[tid + (i << 8)] = dsrc[tid + (i << 8)];
        vcs[tid] = S16 * rcp_clamp(vw[tid]);
    }
    __syncthreads();

    const float* ep = encQ + b * 65536 + (m << 2);
    F4 Ea = ld4(ep);
    F4 Eb = ld4(ep + 1024);
    ep += 2048;

    float acc[4] = {0.f, 0.f, 0.f, 0.f};

    #pragma unroll 4
    for (int o = 0; o < 32; ++o) {
        // always-prefetch next octet; last read lands in decE (in d_ws, unused)
        const F4 Ena = ld4(ep);
        const F4 Enb = ld4(ep + 1024);
        ep += 2048;
        const int u0 = o << 3;
        const F4 ca = ld4(&vcs[u0]);
        const F4 cb = ld4(&vcs[u0 + 4]);
        #pragma unroll
        for (int c = 0; c < 4; ++c) {
            const F4 da = ld4(&dsD[c][u0]);
            const F4 db = ld4(&dsD[c][u0 + 4]);
            const float z0 = fmaf(Ea.v[0], da.v[0], ca.v[0]);
            const float z1 = fmaf(Ea.v[1], da.v[1], ca.v[1]);
            const float z2 = fmaf(Ea.v[2], da.v[2], ca.v[2]);
            const float z3 = fmaf(Ea.v[3], da.v[3], ca.v[3]);
            const float y0 = fmaf(Eb.v[0], db.v[0], cb.v[0]);
            const float y1 = fmaf(Eb.v[1], db.v[1], cb.v[1]);
            const float y2 = fmaf(Eb.v[2], db.v[2], cb.v[2]);
            const float y3 = fmaf(Eb.v[3], db.v[3], cb.v[3]);
            const float pz01 = z0 * z1, pz23 = z2 * z3;
            const float py01 = y0 * y1, py23 = y2 * y3;
            const float nz = fmaf(z0 + z1, pz23, (z2 + z3) * pz01);
            const float ny = fmaf(y0 + y1, py23, (y2 + y3) * py01);
            const float pz = pz01 * pz23, py = py01 * py23;
            const float num = fmaf(nz, py, ny * pz);
            acc[c] = fmaf(num, __builtin_amdgcn_rcpf(pz * py), acc[c]);
        }
        Ea = Ena; Eb = Enb;
    }

    float l[4];
    #pragma unroll
    for (int c = 0; c < 4; ++c) l[c] = acc[c] * LSC;

    // ---- softmax over m (4 waves)
    const int lane = tid & 63, wq = tid >> 6;
    #pragma unroll
    for (int c = 0; c < 4; ++c) {
        float x = l[c];
        #pragma unroll
        for (int off = 32; off > 0; off >>= 1)
            x = fmaxf(x, __shfl_xor(x, off));
        if (lane == 0) redm[c][wq] = x;
    }
    __syncthreads();
    float p[4];
    #pragma unroll
    for (int c = 0; c < 4; ++c) {
        const float mx = fmaxf(fmaxf(redm[c][0], redm[c][1]),
                               fmaxf(redm[c][2], redm[c][3]));
        p[c] = __builtin_amdgcn_exp2f((l[c] - mx) * LOG2E);
    }
    #pragma unroll
    for (int c = 0; c < 4; ++c) {
        float x = p[c];
        #pragma unroll
        for (int off = 32; off > 0; off >>= 1)
            x += __shfl_xor(x, off);
        if (lane == 0) reds[c][wq] = x;
    }
    __syncthreads();
    #pragma unroll
    for (int c = 0; c < 4; ++c) {
        const float s = (reds[c][0] + reds[c][1]) + (reds[c][2] + reds[c][3]);
        const float w = p[c] * __builtin_amdgcn_rcpf(s);
        attn_s[c][m] = w;
        out_attn[(b * 256 + n0 + c) * 256 + m] = w;
    }
    __syncthreads();

    // ---- context: ctx[c][d] = sum_mm attn[c][mm] * enc[b][mm][d], d = m
    const float* eb = enc + b * 65536 + m;
    float cx[4] = {0.f, 0.f, 0.f, 0.f};
    #pragma unroll 4
    for (int mm = 0; mm < 256; mm += 4) {
        const float g0 = eb[(mm + 0) << 8];
        const float g1 = eb[(mm + 1) << 8];
        const float g2 = eb[(mm + 2) << 8];
        const float g3 = eb[(mm + 3) << 8];
        #pragma unroll
        for (int c = 0; c < 4; ++c) {
            const F4 aq = ld4(&attn_s[c][mm]);
            cx[c] = fmaf(aq.v[0], g0, cx[c]);
            cx[c] = fmaf(aq.v[1], g1, cx[c]);
            cx[c] = fmaf(aq.v[2], g2, cx[c]);
            cx[c] = fmaf(aq.v[3], g3, cx[c]);
        }
    }
    #pragma unroll
    for (int c = 0; c < 4; ++c)
        out_ctx[(b * 256 + n0 + c) * 256 + m] = cx[c];
}

extern "C" void kernel_launch(void* const* d_in, const int* in_sizes, int n_in,
                              void* d_out, int out_size, void* d_ws, size_t ws_size,
                              hipStream_t stream) {
    const float* enc = (const float*)d_in[0];
    const float* dec = (const float*)d_in[1];
    const float* W1  = (const float*)d_in[2];
    const float* b1  = (const float*)d_in[3];
    const float* W2  = (const float*)d_in[4];
    const float* b2  = (const float*)d_in[5];
    const float* vw  = (const float*)d_in[6];
    // d_in[7] (v_b) cancels in softmax — unused.

    float* out_ctx  = (float*)d_out;
    float* out_attn = (float*)d_out + 16 * 256 * 256;

    float* encQ = (float*)d_ws;                 // 4 MB
    float* decE = encQ + 16 * 256 * 256;        // 4 MB

    proj_kernel<<<dim3(4, 128), 256, 0, stream>>>(enc, dec, W1, b1, W2, b2, vw, encQ, decE);
    attn_kernel<<<dim3(64, 16), 256, 0, stream>>>(enc, encQ, decE, vw, out_ctx, out_attn);
}

// Round 6
// 147.144 us; speedup vs baseline: 1.1465x; 1.1465x over previous
//
#include <hip/hip_runtime.h>

// RetrosynthesisAttention, B=16, N=M=D=U=256, fp32 — SPLIT-PHASE build (visibility):
//   proj_kernel  : both projection GEMMs + exp2 epilogue (v4-best structure)
//   logit_kernel : l[b,n,m] = LSC * sum_u 1/z_u  (8-way rcp combining, n-tile 8)
//   smctx_kernel : softmax over m + context GEMV (v5 tail)
// Logits staged in the out_attn region, overwritten with weights by smctx.
//
// Math (unchanged): tanh(x) = 1 - 2/(exp2(Kx)+1); constants cancel in softmax.
// z_u = rcpc(v_u)*2^-16 + E'_u*(D_u*rcpc(v_u)), E' = exp2(K*ep-16) precomputed,
// D*rcpc(v) precomputed; sum 1/z over 8 u's with ONE v_rcp (tree combine).

constexpr float KSC   = 2.8853900817779268f;   // 2*log2(e)
constexpr float LOG2E = 1.4426950408889634f;
constexpr float S16   = 1.52587890625e-05f;    // 2^-16
constexpr float LSC   = -3.0517578125e-05f;    // -2^-15

struct F4 { float v[4]; };
__device__ __forceinline__ F4 ld4(const float* p) {
    float4 t = *(const float4*)p;
    F4 r; r.v[0] = t.x; r.v[1] = t.y; r.v[2] = t.z; r.v[3] = t.w; return r;
}
__device__ __forceinline__ float rcp_clamp(float v) {
    float r = __builtin_amdgcn_rcpf(v);
    return fminf(fmaxf(r, -1e4f), 1e4f);   // identical in all kernels
}

// ---------------- Kernel 1: projection GEMMs + exp2 epilogue (v4 structure).
__global__ __launch_bounds__(256) void proj_kernel(
    const float* __restrict__ enc, const float* __restrict__ dec,
    const float* __restrict__ W1,  const float* __restrict__ b1,
    const float* __restrict__ W2,  const float* __restrict__ b2,
    const float* __restrict__ vw,
    float* __restrict__ encQ, float* __restrict__ decE)
{
    __shared__ float Xs[64][33];   // [k][row]
    __shared__ float Ws[64][68];   // [k][u]

    const int tid = threadIdx.x;
    const int tm = tid & 15, tu = tid >> 4;
    const int u0   = blockIdx.x * 64;
    const int row0 = blockIdx.y * 32;          // flat rows 0..8191 (enc|dec)
    const bool is_enc = row0 < 4096;
    const float* X    = is_enc ? enc : dec;
    const float* W    = is_enc ? W1  : W2;
    const float* bias = is_enc ? b1  : b2;
    const int rb = is_enc ? row0 : row0 - 4096;

    float acc[2][4] = {};
    for (int kt = 0; kt < 256; kt += 64) {
        __syncthreads();
        #pragma unroll
        for (int i = 0; i < 2; ++i) {          // X[32 rows][64 k] -> Xs[k][row]
            const int f = tid + (i << 8);
            const int row = f >> 4, kq = (f & 15) << 2;
            F4 x = ld4(&X[(rb + row) * 256 + kt + kq]);
            Xs[kq + 0][row] = x.v[0];
            Xs[kq + 1][row] = x.v[1];
            Xs[kq + 2][row] = x.v[2];
            Xs[kq + 3][row] = x.v[3];
        }
        #pragma unroll
        for (int i = 0; i < 4; ++i) {          // W[64 k][64 u] -> Ws[k][u]
            const int f = tid + (i << 8);
            const int kk = f >> 4, uq = (f & 15) << 2;
            *(float4*)&Ws[kk][uq] = *(const float4*)&W[(kt + kk) * 256 + u0 + uq];
        }
        __syncthreads();
        #pragma unroll 8
        for (int k = 0; k < 64; ++k) {
            const float xa0 = Xs[k][(tm << 1) | 0];
            const float xa1 = Xs[k][(tm << 1) | 1];
            const F4 wa = ld4(&Ws[k][tu << 2]);
            #pragma unroll
            for (int j = 0; j < 4; ++j) {
                acc[0][j] = fmaf(xa0, wa.v[j], acc[0][j]);
                acc[1][j] = fmaf(xa1, wa.v[j], acc[1][j]);
            }
        }
    }

    const int ucol = u0 + (tu << 2);
    const F4 bb = ld4(&bias[ucol]);
    if (is_enc) {
        const int b  = rb >> 8;
        const int m0 = (rb & 255) + (tm << 1);
        const int uq = ucol >> 2;
        #pragma unroll
        for (int i = 0; i < 2; ++i) {
            float4 o;
            o.x = __builtin_amdgcn_exp2f(fmaf(KSC, acc[i][0] + bb.v[0], -16.f));
            o.y = __builtin_amdgcn_exp2f(fmaf(KSC, acc[i][1] + bb.v[1], -16.f));
            o.z = __builtin_amdgcn_exp2f(fmaf(KSC, acc[i][2] + bb.v[2], -16.f));
            o.w = __builtin_amdgcn_exp2f(fmaf(KSC, acc[i][3] + bb.v[3], -16.f));
            *(float4*)&encQ[b * 65536 + uq * 1024 + (m0 + i) * 4] = o;
        }
    } else {
        const F4 vv = ld4(&vw[ucol]);
        float rv[4];
        #pragma unroll
        for (int j = 0; j < 4; ++j) rv[j] = rcp_clamp(vv.v[j]);
        const int r0 = rb + (tm << 1);
        #pragma unroll
        for (int i = 0; i < 2; ++i) {
            float4 o;
            o.x = __builtin_amdgcn_exp2f(KSC * (acc[i][0] + bb.v[0])) * rv[0];
            o.y = __builtin_amdgcn_exp2f(KSC * (acc[i][1] + bb.v[1])) * rv[1];
            o.z = __builtin_amdgcn_exp2f(KSC * (acc[i][2] + bb.v[2])) * rv[2];
            o.w = __builtin_amdgcn_exp2f(KSC * (acc[i][3] + bb.v[3])) * rv[3];
            *(float4*)&decE[(r0 + i) * 256 + ucol] = o;
        }
    }
}

// ---------------- Kernel 2: logits only. n-tile 8, 256 thr, 8-way rcp.
// Grid (32,16) = 512 blocks. Writes raw logits into the out_attn region.
__global__ __launch_bounds__(256) void logit_kernel(
    const float* __restrict__ encQ,  // [b][u/4][m][4] = exp2(K*ep-16)
    const float* __restrict__ decE,  // [n_flat][u]    = exp2(K*dp)*rcpc(v)
    const float* __restrict__ vw,    // [U]
    float* __restrict__ logits)      // [B][N][M] (= out_attn region)
{
    __shared__ float dsD[8][256];
    __shared__ float vcs[256];

    const int tid = threadIdx.x;     // 0..255 = m
    const int b   = blockIdx.y;
    const int n0  = blockIdx.x << 3;
    const int m   = tid;

    {   // stage decE rows n0..n0+7 and vcs = 2^-16 * rcpc(v)
        const float* dsrc = decE + (b * 256 + n0) * 256;
        #pragma unroll
        for (int i = 0; i < 8; ++i)
            ((float*)dsD)[tid + (i << 8)] = dsrc[tid + (i << 8)];
        vcs[tid] = S16 * rcp_clamp(vw[tid]);
    }
    __syncthreads();

    const float* ep = encQ + b * 65536 + (m << 2);
    F4 Ea = ld4(ep);
    F4 Eb = ld4(ep + 1024);
    ep += 2048;

    float acc[8] = {};

    #pragma unroll 2
    for (int o = 0; o < 32; ++o) {
        // always-prefetch next octet; final read spills into decE (harmless)
        const F4 Ena = ld4(ep);
        const F4 Enb = ld4(ep + 1024);
        ep += 2048;
        const int u0 = o << 3;
        const F4 ca = ld4(&vcs[u0]);
        const F4 cb = ld4(&vcs[u0 + 4]);
        #pragma unroll
        for (int c = 0; c < 8; ++c) {
            const F4 da = ld4(&dsD[c][u0]);
            const F4 db = ld4(&dsD[c][u0 + 4]);
            const float z0 = fmaf(Ea.v[0], da.v[0], ca.v[0]);
            const float z1 = fmaf(Ea.v[1], da.v[1], ca.v[1]);
            const float z2 = fmaf(Ea.v[2], da.v[2], ca.v[2]);
            const float z3 = fmaf(Ea.v[3], da.v[3], ca.v[3]);
            const float y0 = fmaf(Eb.v[0], db.v[0], cb.v[0]);
            const float y1 = fmaf(Eb.v[1], db.v[1], cb.v[1]);
            const float y2 = fmaf(Eb.v[2], db.v[2], cb.v[2]);
            const float y3 = fmaf(Eb.v[3], db.v[3], cb.v[3]);
            const float pz01 = z0 * z1, pz23 = z2 * z3;
            const float py01 = y0 * y1, py23 = y2 * y3;
            const float nz = fmaf(z0 + z1, pz23, (z2 + z3) * pz01);
            const float ny = fmaf(y0 + y1, py23, (y2 + y3) * py01);
            const float pz = pz01 * pz23, py = py01 * py23;
            const float num = fmaf(nz, py, ny * pz);
            acc[c] = fmaf(num, __builtin_amdgcn_rcpf(pz * py), acc[c]);
        }
        Ea = Ena; Eb = Enb;
    }

    #pragma unroll
    for (int c = 0; c < 8; ++c)
        logits[(b * 256 + n0 + c) * 256 + m] = acc[c] * LSC;
}

// ---------------- Kernel 3: softmax + context (v5 tail). Grid (64,16), 256 thr.
// Reads logits from out_attn region, overwrites with weights, writes ctx.
__global__ __launch_bounds__(256) void smctx_kernel(
    const float* __restrict__ enc,   // [B][M][D]
    float* __restrict__ out_attn,    // in: logits, out: weights
    float* __restrict__ out_ctx)     // [B][N][D]
{
    __shared__ float attn_s[4][256];
    __shared__ float redm[4][4], reds[4][4];

    const int tid = threadIdx.x;     // 0..255
    const int b   = blockIdx.y;
    const int n0  = blockIdx.x << 2;
    const int m   = tid;

    float l[4];
    #pragma unroll
    for (int c = 0; c < 4; ++c)
        l[c] = out_attn[(b * 256 + n0 + c) * 256 + m];

    // ---- softmax over m (4 waves)
    const int lane = tid & 63, wq = tid >> 6;
    #pragma unroll
    for (int c = 0; c < 4; ++c) {
        float x = l[c];
        #pragma unroll
        for (int off = 32; off > 0; off >>= 1)
            x = fmaxf(x, __shfl_xor(x, off));
        if (lane == 0) redm[c][wq] = x;
    }
    __syncthreads();
    float p[4];
    #pragma unroll
    for (int c = 0; c < 4; ++c) {
        const float mx = fmaxf(fmaxf(redm[c][0], redm[c][1]),
                               fmaxf(redm[c][2], redm[c][3]));
        p[c] = __builtin_amdgcn_exp2f((l[c] - mx) * LOG2E);
    }
    #pragma unroll
    for (int c = 0; c < 4; ++c) {
        float x = p[c];
        #pragma unroll
        for (int off = 32; off > 0; off >>= 1)
            x += __shfl_xor(x, off);
        if (lane == 0) reds[c][wq] = x;
    }
    __syncthreads();
    #pragma unroll
    for (int c = 0; c < 4; ++c) {
        const float s = (reds[c][0] + reds[c][1]) + (reds[c][2] + reds[c][3]);
        const float w = p[c] * __builtin_amdgcn_rcpf(s);
        attn_s[c][m] = w;
        out_attn[(b * 256 + n0 + c) * 256 + m] = w;
    }
    __syncthreads();

    // ---- context: ctx[c][d] = sum_mm attn[c][mm] * enc[b][mm][d], d = m
    const float* eb = enc + b * 65536 + m;
    float cx[4] = {};
    #pragma unroll 4
    for (int mm = 0; mm < 256; mm += 4) {
        const float g0 = eb[(mm + 0) << 8];
        const float g1 = eb[(mm + 1) << 8];
        const float g2 = eb[(mm + 2) << 8];
        const float g3 = eb[(mm + 3) << 8];
        #pragma unroll
        for (int c = 0; c < 4; ++c) {
            const F4 aq = ld4(&attn_s[c][mm]);
            cx[c] = fmaf(aq.v[0], g0, cx[c]);
            cx[c] = fmaf(aq.v[1], g1, cx[c]);
            cx[c] = fmaf(aq.v[2], g2, cx[c]);
            cx[c] = fmaf(aq.v[3], g3, cx[c]);
        }
    }
    #pragma unroll
    for (int c = 0; c < 4; ++c)
        out_ctx[(b * 256 + n0 + c) * 256 + m] = cx[c];
}

extern "C" void kernel_launch(void* const* d_in, const int* in_sizes, int n_in,
                              void* d_out, int out_size, void* d_ws, size_t ws_size,
                              hipStream_t stream) {
    const float* enc = (const float*)d_in[0];
    const float* dec = (const float*)d_in[1];
    const float* W1  = (const float*)d_in[2];
    const float* b1  = (const float*)d_in[3];
    const float* W2  = (const float*)d_in[4];
    const float* b2  = (const float*)d_in[5];
    const float* vw  = (const float*)d_in[6];
    // d_in[7] (v_b) cancels in softmax — unused.

    float* out_ctx  = (float*)d_out;
    float* out_attn = (float*)d_out + 16 * 256 * 256;

    float* encQ = (float*)d_ws;                 // 4 MB
    float* decE = encQ + 16 * 256 * 256;        // 4 MB

    proj_kernel <<<dim3(4, 256), 256, 0, stream>>>(enc, dec, W1, b1, W2, b2, vw, encQ, decE);
    logit_kernel<<<dim3(32, 16), 256, 0, stream>>>(encQ, decE, vw, out_attn);
    smctx_kernel<<<dim3(64, 16), 256, 0, stream>>>(enc, out_attn, out_ctx);
}

// Round 7
// 143.129 us; speedup vs baseline: 1.1787x; 1.0281x over previous
//
#include <hip/hip_runtime.h>

// RetrosynthesisAttention, B=16, N=M=D=U=256, fp32 — split-phase build:
//   proj_kernel  : both projection GEMMs + exp2 epilogue (v4 structure, control)
//   logit_kernel : l[b,n,m] = LSC * sum_u 1/z_u (8-way rcp, n-tile 8, 512 thr)
//   smctx_kernel : softmax over m + context GEMV (n-tile 8, 512 thr)
// Logits staged in out_attn region, overwritten with weights by smctx.
//
// Math: tanh(x) = 1 - 2/(exp2(Kx)+1); constants cancel in softmax.
// z_u = rcpc(v_u)*2^-16 + E'_u*(D_u*rcpc(v_u)), E' = exp2(K*ep-16), D*rcpc(v)
// precomputed; sum 1/z over 8 u's with ONE v_rcp (tree combine).

constexpr float KSC   = 2.8853900817779268f;   // 2*log2(e)
constexpr float LOG2E = 1.4426950408889634f;
constexpr float S16   = 1.52587890625e-05f;    // 2^-16
constexpr float LSC   = -3.0517578125e-05f;    // -2^-15

struct F4 { float v[4]; };
__device__ __forceinline__ F4 ld4(const float* p) {
    float4 t = *(const float4*)p;
    F4 r; r.v[0] = t.x; r.v[1] = t.y; r.v[2] = t.z; r.v[3] = t.w; return r;
}
__device__ __forceinline__ float rcp_clamp(float v) {
    float r = __builtin_amdgcn_rcpf(v);
    return fminf(fmaxf(r, -1e4f), 1e4f);   // identical in all kernels
}

// ---------------- Kernel 1: projection GEMMs + exp2 epilogue (unchanged control).
__global__ __launch_bounds__(256) void proj_kernel(
    const float* __restrict__ enc, const float* __restrict__ dec,
    const float* __restrict__ W1,  const float* __restrict__ b1,
    const float* __restrict__ W2,  const float* __restrict__ b2,
    const float* __restrict__ vw,
    float* __restrict__ encQ, float* __restrict__ decE)
{
    __shared__ float Xs[64][33];   // [k][row]
    __shared__ float Ws[64][68];   // [k][u]

    const int tid = threadIdx.x;
    const int tm = tid & 15, tu = tid >> 4;
    const int u0   = blockIdx.x * 64;
    const int row0 = blockIdx.y * 32;          // flat rows 0..8191 (enc|dec)
    const bool is_enc = row0 < 4096;
    const float* X    = is_enc ? enc : dec;
    const float* W    = is_enc ? W1  : W2;
    const float* bias = is_enc ? b1  : b2;
    const int rb = is_enc ? row0 : row0 - 4096;

    float acc[2][4] = {};
    for (int kt = 0; kt < 256; kt += 64) {
        __syncthreads();
        #pragma unroll
        for (int i = 0; i < 2; ++i) {          // X[32 rows][64 k] -> Xs[k][row]
            const int f = tid + (i << 8);
            const int row = f >> 4, kq = (f & 15) << 2;
            F4 x = ld4(&X[(rb + row) * 256 + kt + kq]);
            Xs[kq + 0][row] = x.v[0];
            Xs[kq + 1][row] = x.v[1];
            Xs[kq + 2][row] = x.v[2];
            Xs[kq + 3][row] = x.v[3];
        }
        #pragma unroll
        for (int i = 0; i < 4; ++i) {          // W[64 k][64 u] -> Ws[k][u]
            const int f = tid + (i << 8);
            const int kk = f >> 4, uq = (f & 15) << 2;
            *(float4*)&Ws[kk][uq] = *(const float4*)&W[(kt + kk) * 256 + u0 + uq];
        }
        __syncthreads();
        #pragma unroll 8
        for (int k = 0; k < 64; ++k) {
            const float xa0 = Xs[k][(tm << 1) | 0];
            const float xa1 = Xs[k][(tm << 1) | 1];
            const F4 wa = ld4(&Ws[k][tu << 2]);
            #pragma unroll
            for (int j = 0; j < 4; ++j) {
                acc[0][j] = fmaf(xa0, wa.v[j], acc[0][j]);
                acc[1][j] = fmaf(xa1, wa.v[j], acc[1][j]);
            }
        }
    }

    const int ucol = u0 + (tu << 2);
    const F4 bb = ld4(&bias[ucol]);
    if (is_enc) {
        const int b  = rb >> 8;
        const int m0 = (rb & 255) + (tm << 1);
        const int uq = ucol >> 2;
        #pragma unroll
        for (int i = 0; i < 2; ++i) {
            float4 o;
            o.x = __builtin_amdgcn_exp2f(fmaf(KSC, acc[i][0] + bb.v[0], -16.f));
            o.y = __builtin_amdgcn_exp2f(fmaf(KSC, acc[i][1] + bb.v[1], -16.f));
            o.z = __builtin_amdgcn_exp2f(fmaf(KSC, acc[i][2] + bb.v[2], -16.f));
            o.w = __builtin_amdgcn_exp2f(fmaf(KSC, acc[i][3] + bb.v[3], -16.f));
            *(float4*)&encQ[b * 65536 + uq * 1024 + (m0 + i) * 4] = o;
        }
    } else {
        const F4 vv = ld4(&vw[ucol]);
        float rv[4];
        #pragma unroll
        for (int j = 0; j < 4; ++j) rv[j] = rcp_clamp(vv.v[j]);
        const int r0 = rb + (tm << 1);
        #pragma unroll
        for (int i = 0; i < 2; ++i) {
            float4 o;
            o.x = __builtin_amdgcn_exp2f(KSC * (acc[i][0] + bb.v[0])) * rv[0];
            o.y = __builtin_amdgcn_exp2f(KSC * (acc[i][1] + bb.v[1])) * rv[1];
            o.z = __builtin_amdgcn_exp2f(KSC * (acc[i][2] + bb.v[2])) * rv[2];
            o.w = __builtin_amdgcn_exp2f(KSC * (acc[i][3] + bb.v[3])) * rv[3];
            *(float4*)&decE[(r0 + i) * 256 + ucol] = o;
        }
    }
}

// ---------------- Kernel 2: logits. 512 thr (8 waves), n-tile 8: half h owns
// chains t0=4h..4h+3; m = tid&255 (both halves stream same E lines -> L1).
// Grid (32,16)=512 blocks -> 2 blk/CU, 16 waves/CU (50% theoretical).
__global__ __launch_bounds__(512) void logit_kernel(
    const float* __restrict__ encQ,  // [b][u/4][m][4] = exp2(K*ep-16)
    const float* __restrict__ decE,  // [n_flat][u]    = exp2(K*dp)*rcpc(v)
    const float* __restrict__ vw,    // [U]
    float* __restrict__ logits)      // [B][N][M] (= out_attn region)
{
    __shared__ float dsD[8][256];
    __shared__ float vcs[256];

    const int tid = threadIdx.x;     // 0..511
    const int b   = blockIdx.y;
    const int n0  = blockIdx.x << 3;
    const int h   = tid >> 8;
    const int m   = tid & 255;
    const int t0  = h << 2;

    {   // stage decE rows n0..n0+7 and vcs = 2^-16 * rcpc(v)
        const float* dsrc = decE + (b * 256 + n0) * 256;
        #pragma unroll
        for (int i = 0; i < 4; ++i)
            ((float*)dsD)[tid + (i << 9)] = dsrc[tid + (i << 9)];
        if (tid < 256) vcs[tid] = S16 * rcp_clamp(vw[tid]);
    }
    __syncthreads();

    const float* ep = encQ + b * 65536 + (m << 2);
    F4 Ea = ld4(ep);
    F4 Eb = ld4(ep + 1024);
    ep += 2048;

    float acc[4] = {};

    #pragma unroll 4
    for (int o = 0; o < 32; ++o) {
        // always-prefetch next octet; final read spills into decE (harmless)
        const F4 Ena = ld4(ep);
        const F4 Enb = ld4(ep + 1024);
        ep += 2048;
        const int u0 = o << 3;
        const F4 ca = ld4(&vcs[u0]);
        const F4 cb = ld4(&vcs[u0 + 4]);
        #pragma unroll
        for (int c = 0; c < 4; ++c) {
            const F4 da = ld4(&dsD[t0 + c][u0]);
            const F4 db = ld4(&dsD[t0 + c][u0 + 4]);
            const float z0 = fmaf(Ea.v[0], da.v[0], ca.v[0]);
            const float z1 = fmaf(Ea.v[1], da.v[1], ca.v[1]);
            const float z2 = fmaf(Ea.v[2], da.v[2], ca.v[2]);
            const float z3 = fmaf(Ea.v[3], da.v[3], ca.v[3]);
            const float y0 = fmaf(Eb.v[0], db.v[0], cb.v[0]);
            const float y1 = fmaf(Eb.v[1], db.v[1], cb.v[1]);
            const float y2 = fmaf(Eb.v[2], db.v[2], cb.v[2]);
            const float y3 = fmaf(Eb.v[3], db.v[3], cb.v[3]);
            const float pz01 = z0 * z1, pz23 = z2 * z3;
            const float py01 = y0 * y1, py23 = y2 * y3;
            const float nz = fmaf(z0 + z1, pz23, (z2 + z3) * pz01);
            const float ny = fmaf(y0 + y1, py23, (y2 + y3) * py01);
            const float pz = pz01 * pz23, py = py01 * py23;
            const float num = fmaf(nz, py, ny * pz);
            acc[c] = fmaf(num, __builtin_amdgcn_rcpf(pz * py), acc[c]);
        }
        Ea = Ena; Eb = Enb;
    }

    #pragma unroll
    for (int c = 0; c < 4; ++c)
        logits[(b * 256 + n0 + t0 + c) * 256 + m] = acc[c] * LSC;
}

// ---------------- Kernel 3: softmax + context. 512 thr, n-tile 8 (halves own
// 4 chains). Grid (32,16)=512 blocks. enc lines shared across 8 chains.
__global__ __launch_bounds__(512) void smctx_kernel(
    const float* __restrict__ enc,   // [B][M][D]
    float* __restrict__ out_attn,    // in: logits, out: weights
    float* __restrict__ out_ctx)     // [B][N][D]
{
    __shared__ float attn_s[8][256];
    __shared__ float redm[8][4], reds[8][4];

    const int tid = threadIdx.x;     // 0..511
    const int b   = blockIdx.y;
    const int n0  = blockIdx.x << 3;
    const int h   = tid >> 8;
    const int m   = tid & 255;
    const int t0  = h << 2;

    float l[4];
    #pragma unroll
    for (int c = 0; c < 4; ++c)
        l[c] = out_attn[(b * 256 + n0 + t0 + c) * 256 + m];

    // ---- softmax over m (4 waves per half)
    const int lane = tid & 63, wq = (tid >> 6) & 3;
    #pragma unroll
    for (int c = 0; c < 4; ++c) {
        float x = l[c];
        #pragma unroll
        for (int off = 32; off > 0; off >>= 1)
            x = fmaxf(x, __shfl_xor(x, off));
        if (lane == 0) redm[t0 + c][wq] = x;
    }
    __syncthreads();
    float p[4];
    #pragma unroll
    for (int c = 0; c < 4; ++c) {
        const float mx = fmaxf(fmaxf(redm[t0 + c][0], redm[t0 + c][1]),
                               fmaxf(redm[t0 + c][2], redm[t0 + c][3]));
        p[c] = __builtin_amdgcn_exp2f((l[c] - mx) * LOG2E);
    }
    #pragma unroll
    for (int c = 0; c < 4; ++c) {
        float x = p[c];
        #pragma unroll
        for (int off = 32; off > 0; off >>= 1)
            x += __shfl_xor(x, off);
        if (lane == 0) reds[t0 + c][wq] = x;
    }
    __syncthreads();
    #pragma unroll
    for (int c = 0; c < 4; ++c) {
        const float s = (reds[t0 + c][0] + reds[t0 + c][1])
                      + (reds[t0 + c][2] + reds[t0 + c][3]);
        const float w = p[c] * __builtin_amdgcn_rcpf(s);
        attn_s[t0 + c][m] = w;
        out_attn[(b * 256 + n0 + t0 + c) * 256 + m] = w;
    }
    __syncthreads();

    // ---- context: ctx[c][d] = sum_mm attn[c][mm] * enc[b][mm][d], d = m
    const float* eb = enc + b * 65536 + m;
    float cx[4] = {};
    #pragma unroll 4
    for (int mm = 0; mm < 256; mm += 4) {
        const float g0 = eb[(mm + 0) << 8];
        const float g1 = eb[(mm + 1) << 8];
        const float g2 = eb[(mm + 2) << 8];
        const float g3 = eb[(mm + 3) << 8];
        #pragma unroll
        for (int c = 0; c < 4; ++c) {
            const F4 aq = ld4(&attn_s[t0 + c][mm]);
            cx[c] = fmaf(aq.v[0], g0, cx[c]);
            cx[c] = fmaf(aq.v[1], g1, cx[c]);
            cx[c] = fmaf(aq.v[2], g2, cx[c]);
            cx[c] = fmaf(aq.v[3], g3, cx[c]);
        }
    }
    #pragma unroll
    for (int c = 0; c < 4; ++c)
        out_ctx[(b * 256 + n0 + t0 + c) * 256 + m] = cx[c];
}

extern "C" void kernel_launch(void* const* d_in, const int* in_sizes, int n_in,
                              void* d_out, int out_size, void* d_ws, size_t ws_size,
                              hipStream_t stream) {
    const float* enc = (const float*)d_in[0];
    const float* dec = (const float*)d_in[1];
    const float* W1  = (const float*)d_in[2];
    const float* b1  = (const float*)d_in[3];
    const float* W2  = (const float*)d_in[4];
    const float* b2  = (const float*)d_in[5];
    const float* vw  = (const float*)d_in[6];
    // d_in[7] (v_b) cancels in softmax — unused.

    float* out_ctx  = (float*)d_out;
    float* out_attn = (float*)d_out + 16 * 256 * 256;

    float* encQ = (float*)d_ws;                 // 4 MB
    float* decE = encQ + 16 * 256 * 256;        // 4 MB

    proj_kernel <<<dim3(4, 256), 256, 0, stream>>>(enc, dec, W1, b1, W2, b2, vw, encQ, decE);
    logit_kernel<<<dim3(32, 16), 512, 0, stream>>>(encQ, decE, vw, out_attn);
    smctx_kernel<<<dim3(32, 16), 512, 0, stream>>>(enc, out_attn, out_ctx);
}